// Round 2
// baseline (246.773 us; speedup 1.0000x reference)
//
#include <hip/hip_runtime.h>
#include <math.h>

#define BATCH 8192
#define SENTS 50
#define ED    256
#define NENT  20
#define BB    16

// log2(200)/256
#define RATE_K 0.0298588132413075f

// ---------------------------------------------------------------------------
// Kernel 0: precompute pos[s][e] = sin(s * 200^(-e/256)) into ws table
// ---------------------------------------------------------------------------
__global__ __launch_bounds__(256) void pos_kernel(float* __restrict__ pos_tab) {
    int s = blockIdx.x;
    int e = threadIdx.x;
    float rate = exp2f(-(float)e * RATE_K);
    pos_tab[s * ED + e] = sinf((float)s * rate);
}

// ---------------------------------------------------------------------------
// Kernel 1: per-batch streaming, x held in REGISTERS.
// Thread (sr = t>>6, c = t&63) owns float4 columns [4c..4c+3] of rows
// s = sr + 4k (k = 0..12).  LDS only for q-broadcast + small reduces (~10KB).
// ---------------------------------------------------------------------------
__global__ __launch_bounds__(256, 5) void main_kernel(
    const float* __restrict__ sents, const float* __restrict__ entities,
    const float* __restrict__ dense_w, const float* __restrict__ pos_tab,
    float* __restrict__ h_out, float* __restrict__ m_out)
{
    __shared__ __align__(16) float4 qs[64];
    __shared__ __align__(16) float4 part[4][64];
    __shared__ __align__(16) float4 parte[4][64];
    __shared__ float logit_s[64];
    __shared__ float coef[64];

    int t  = threadIdx.x;
    int b  = blockIdx.x;
    int c  = t & 63;     // colgroup 0..63 (lane)
    int sr = t >> 6;     // row residue == wave id

    const float4* s4 = (const float4*)(sents + (size_t)b * SENTS * ED);
    const float4* p4 = (const float4*)pos_tab;
    const float4* e4 = (const float4*)(entities + (size_t)b * NENT * ED);

    // ---- load x rows into registers (coalesced float4) ----
    float4 x[13];
    #pragma unroll
    for (int k = 0; k < 13; ++k) {
        int s = sr + 4 * k;
        if (s < SENTS) {
            float4 v = s4[s * 64 + c];
            float4 p = p4[s * 64 + c];
            v.x += p.x; v.y += p.y; v.z += p.z; v.w += p.w;
            x[k] = v;
        } else {
            x[k] = make_float4(0.f, 0.f, 0.f, 0.f);
        }
    }

    // ---- entity partial sum: rows n = sr + 4k, k = 0..4 (covers 0..19) ----
    float4 es = make_float4(0.f, 0.f, 0.f, 0.f);
    #pragma unroll
    for (int n = 0; n < 5; ++n) {
        float4 v = e4[(sr + 4 * n) * 64 + c];
        es.x += v.x; es.y += v.y; es.z += v.z; es.w += v.w;
    }

    // ---- broadcast q = x[49] (owned by sr==1, k==12) ----
    if (sr == 1) qs[c] = x[12];
    __syncthreads();
    float4 q = qs[c];

    // ---- logits: per wave, shfl-reduce dot(x[s], q) over 64 lanes ----
    #pragma unroll
    for (int k = 0; k < 13; ++k) {
        int s = sr + 4 * k;
        if (s < SENTS) {
            float4 v = x[k];
            float p = v.x * q.x + v.y * q.y + v.z * q.z + v.w * q.w;
            p += __shfl_down(p, 32);
            p += __shfl_down(p, 16);
            p += __shfl_down(p, 8);
            p += __shfl_down(p, 4);
            p += __shfl_down(p, 2);
            p += __shfl_down(p, 1);
            if (c == 0) logit_s[s] = p;
        }
    }
    __syncthreads();

    // ---- softmax over 50 logits (wave 0) ----
    if (sr == 0) {
        float l = (c < SENTS) ? logit_s[c] : -INFINITY;
        float mx = l;
        for (int off = 32; off >= 1; off >>= 1) mx = fmaxf(mx, __shfl_xor(mx, off));
        float ex = (c < SENTS) ? expf(l - mx) : 0.f;
        float sm = ex;
        for (int off = 32; off >= 1; off >>= 1) sm += __shfl_xor(sm, off);
        if (c < SENTS) coef[c] = ex / sm;
    }
    __syncthreads();

    // ---- h partial: sum over this thread's rows ----
    float4 h = make_float4(0.f, 0.f, 0.f, 0.f);
    #pragma unroll
    for (int k = 0; k < 13; ++k) {
        int s = sr + 4 * k;
        if (s < SENTS) {
            float cf = coef[s];
            h.x += cf * x[k].x; h.y += cf * x[k].y;
            h.z += cf * x[k].z; h.w += cf * x[k].w;
        }
    }
    part[sr][c]  = h;
    parte[sr][c] = es;
    __syncthreads();

    // ---- 4-way residue reduce + write (waves 0 and 1) ----
    if (sr == 0) {
        float4 a0 = part[0][c], a1 = part[1][c], a2 = part[2][c], a3 = part[3][c];
        float4 r;
        r.x = a0.x + a1.x + a2.x + a3.x;
        r.y = a0.y + a1.y + a2.y + a3.y;
        r.z = a0.z + a1.z + a2.z + a3.z;
        r.w = a0.w + a1.w + a2.w + a3.w;
        ((float4*)(h_out + (size_t)b * ED))[c] = r;
    } else if (sr == 1) {
        float4 a0 = parte[0][c], a1 = parte[1][c], a2 = parte[2][c], a3 = parte[3][c];
        float4 w4 = ((const float4*)dense_w)[c];
        float4 r;
        r.x = (a0.x + a1.x + a2.x + a3.x) * w4.x;
        r.y = (a0.y + a1.y + a2.y + a3.y) * w4.y;
        r.z = (a0.z + a1.z + a2.z + a3.z) * w4.z;
        r.w = (a0.w + a1.w + a2.w + a3.w) * w4.w;
        ((float4*)(m_out + (size_t)b * ED))[c] = r;
    }
}

// ---------------------------------------------------------------------------
// Kernel 2: out[b] = sigmoid( sum_e (sum_e' h[e'] A[e',e]) * m[e] + bias )
// BB batches per block; coalesced column reads of A (L2-resident).
// ---------------------------------------------------------------------------
__global__ __launch_bounds__(256) void bilinear_kernel(
    const float* __restrict__ hws, const float* __restrict__ mws,
    const float* __restrict__ A, const float* __restrict__ dense_b,
    float* __restrict__ out)
{
    __shared__ __align__(16) float hl[BB][ED];
    __shared__ float ml[BB][ED];
    __shared__ float part[BB][ED];

    int t  = threadIdx.x;
    int b0 = blockIdx.x * BB;

    for (int i = 0; i < BB; ++i) {
        hl[i][t] = hws[(size_t)(b0 + i) * ED + t];
        ml[i][t] = mws[(size_t)(b0 + i) * ED + t];
    }
    __syncthreads();

    float acc[BB];
    #pragma unroll
    for (int i = 0; i < BB; ++i) acc[i] = 0.f;

    for (int ep = 0; ep < ED; ep += 4) {
        float a0 = A[(ep + 0) * ED + t];
        float a1 = A[(ep + 1) * ED + t];
        float a2 = A[(ep + 2) * ED + t];
        float a3 = A[(ep + 3) * ED + t];
        #pragma unroll
        for (int i = 0; i < BB; ++i) {
            float4 hv = *(const float4*)&hl[i][ep];
            acc[i] += hv.x * a0 + hv.y * a1 + hv.z * a2 + hv.w * a3;
        }
    }

    #pragma unroll
    for (int i = 0; i < BB; ++i) part[i][t] = acc[i] * ml[i][t];
    __syncthreads();

    int lane = t & 63, w = t >> 6;
    float bias = dense_b[0];
    for (int i = w; i < BB; i += 4) {
        float v = part[i][lane] + part[i][lane + 64] + part[i][lane + 128] + part[i][lane + 192];
        for (int off = 32; off >= 1; off >>= 1) v += __shfl_xor(v, off);
        if (lane == 0) out[b0 + i] = 1.f / (1.f + expf(-(v + bias)));
    }
}

// ---------------------------------------------------------------------------
// Fallback: fully fused, no workspace (in case ws_size is tiny)
// ---------------------------------------------------------------------------
__global__ __launch_bounds__(256) void fused_kernel(
    const float* __restrict__ sents, const float* __restrict__ entities,
    const float* __restrict__ A, const float* __restrict__ dense_w,
    const float* __restrict__ dense_b, float* __restrict__ out)
{
    __shared__ __align__(16) float xs[SENTS][ED + 4];
    __shared__ float logit_s[64];
    __shared__ float coef[64];
    __shared__ __align__(16) float harr[ED];
    __shared__ float marr[ED];
    __shared__ float red[4];

    int t    = threadIdx.x;
    int b    = blockIdx.x;
    int lane = t & 63;
    int w    = t >> 6;

    float rate = exp2f(-(float)t * RATE_K);
    const float* sp = sents + (size_t)b * SENTS * ED;
    for (int s = 0; s < SENTS; ++s)
        xs[s][t] = sp[s * ED + t] + sinf((float)s * rate);
    __syncthreads();

    float4 q = *(const float4*)&xs[SENTS - 1][lane * 4];
    for (int s = w; s < SENTS; s += 4) {
        float4 v = *(const float4*)&xs[s][lane * 4];
        float p = v.x * q.x + v.y * q.y + v.z * q.z + v.w * q.w;
        p += __shfl_down(p, 32);
        p += __shfl_down(p, 16);
        p += __shfl_down(p, 8);
        p += __shfl_down(p, 4);
        p += __shfl_down(p, 2);
        p += __shfl_down(p, 1);
        if (lane == 0) logit_s[s] = p;
    }
    __syncthreads();

    if (w == 0) {
        float l = (lane < SENTS) ? logit_s[lane] : -INFINITY;
        float mx = l;
        for (int off = 32; off >= 1; off >>= 1) mx = fmaxf(mx, __shfl_xor(mx, off));
        float ex = (lane < SENTS) ? expf(l - mx) : 0.f;
        float sm = ex;
        for (int off = 32; off >= 1; off >>= 1) sm += __shfl_xor(sm, off);
        if (lane < SENTS) coef[lane] = ex / sm;
    }
    __syncthreads();

    float h = 0.f;
    #pragma unroll
    for (int s = 0; s < SENTS; ++s) h += coef[s] * xs[s][t];

    const float* ent = entities + (size_t)b * NENT * ED;
    float es = 0.f;
    #pragma unroll
    for (int n = 0; n < NENT; ++n) es += ent[n * ED + t];
    float m = es * dense_w[t];

    harr[t] = h;
    marr[t] = m;
    __syncthreads();

    float acc = 0.f;
    for (int ep = 0; ep < ED; ep += 4) {
        float4 hv = *(const float4*)&harr[ep];
        acc += hv.x * A[(ep + 0) * ED + t];
        acc += hv.y * A[(ep + 1) * ED + t];
        acc += hv.z * A[(ep + 2) * ED + t];
        acc += hv.w * A[(ep + 3) * ED + t];
    }
    float val = acc * marr[t];
    val += __shfl_down(val, 32);
    val += __shfl_down(val, 16);
    val += __shfl_down(val, 8);
    val += __shfl_down(val, 4);
    val += __shfl_down(val, 2);
    val += __shfl_down(val, 1);
    if (lane == 0) red[w] = val;
    __syncthreads();
    if (t == 0) {
        float tot = red[0] + red[1] + red[2] + red[3];
        out[b] = 1.f / (1.f + expf(-(tot + dense_b[0])));
    }
}

extern "C" void kernel_launch(void* const* d_in, const int* in_sizes, int n_in,
                              void* d_out, int out_size, void* d_ws, size_t ws_size,
                              hipStream_t stream) {
    const float* sents    = (const float*)d_in[0];
    const float* entities = (const float*)d_in[1];
    const float* A        = (const float*)d_in[2];
    const float* dense_w  = (const float*)d_in[3];
    const float* dense_b  = (const float*)d_in[4];
    float* out = (float*)d_out;

    size_t pos_bytes = (size_t)SENTS * ED * sizeof(float);          // 51200
    size_t hm_bytes  = (size_t)BATCH * ED * sizeof(float);          // 8 MB each
    size_t need = pos_bytes + 2 * hm_bytes;

    if (ws_size >= need) {
        float* pos_tab = (float*)d_ws;
        float* hws = (float*)((char*)d_ws + pos_bytes);
        float* mws = (float*)((char*)d_ws + pos_bytes + hm_bytes);
        pos_kernel<<<SENTS, ED, 0, stream>>>(pos_tab);
        main_kernel<<<BATCH, 256, 0, stream>>>(sents, entities, dense_w, pos_tab, hws, mws);
        bilinear_kernel<<<BATCH / BB, 256, 0, stream>>>(hws, mws, A, dense_b, out);
    } else {
        fused_kernel<<<BATCH, 256, 0, stream>>>(sents, entities, A, dense_w, dense_b, out);
    }
}

// Round 3
// 162.073 us; speedup vs baseline: 1.5226x; 1.5226x over previous
//
#include <hip/hip_runtime.h>
#include <math.h>

#define BATCH 8192
#define SENTS 50
#define ED    256
#define NENT  20
#define BB    16

// log2(200)/256
#define RATE_K 0.0298588132413075f

// ---------------------------------------------------------------------------
// Kernel 0: precompute pos[s][e] = sin(s * 200^(-e/256)) into ws table
// ---------------------------------------------------------------------------
__global__ __launch_bounds__(256) void pos_kernel(float* __restrict__ pos_tab) {
    int s = blockIdx.x;
    int e = threadIdx.x;
    float rate = exp2f(-(float)e * RATE_K);
    pos_tab[s * ED + e] = sinf((float)s * rate);
}

// ---------------------------------------------------------------------------
// Kernel 1: per-batch streaming, x in registers, ALL loads issued up front
// (no launch_bounds reg cap — MLP over TLP). Thread (sr=t>>6, c=t&63) owns
// float4 colgroup c of rows s = sr+4k. No barrier before/during load phase.
// ---------------------------------------------------------------------------
__global__ __launch_bounds__(256) void main_kernel(
    const float* __restrict__ sents, const float* __restrict__ entities,
    const float* __restrict__ dense_w, const float* __restrict__ pos_tab,
    float* __restrict__ h_out, float* __restrict__ m_out)
{
    __shared__ float logit_s[64];
    __shared__ float coef[64];
    __shared__ __align__(16) float4 part[4][64];
    __shared__ __align__(16) float4 parte[4][64];

    int t  = threadIdx.x;
    int b  = blockIdx.x;
    int c  = t & 63;     // colgroup (lane)
    int sr = t >> 6;     // row residue == wave id

    const float4* s4 = (const float4*)(sents + (size_t)b * SENTS * ED);
    const float4* p4 = (const float4*)pos_tab;
    const float4* e4 = (const float4*)(entities + (size_t)b * NENT * ED);

    bool has13 = (sr < 2);   // rows 48 (sr=0) and 49 (sr=1)

    // ---- issue ALL global loads as straight-line unrolled code ----
    float4 xv[13], pv[13], ev[5];
    #pragma unroll
    for (int k = 0; k < 12; ++k) xv[k] = s4[(sr + 4 * k) * 64 + c];
    float4 qsv = s4[49 * 64 + c];          // q row, redundant per wave (L1 hit)
    float4 qpv = p4[49 * 64 + c];
    #pragma unroll
    for (int k = 0; k < 12; ++k) pv[k] = p4[(sr + 4 * k) * 64 + c];
    #pragma unroll
    for (int n = 0; n < 5; ++n) ev[n] = e4[(sr + 4 * n) * 64 + c];
    if (has13) {
        xv[12] = s4[(sr + 48) * 64 + c];
        pv[12] = p4[(sr + 48) * 64 + c];
    }

    // ---- x = sents + pos (registers) ----
    float4 x[13];
    #pragma unroll
    for (int k = 0; k < 12; ++k) {
        x[k].x = xv[k].x + pv[k].x; x[k].y = xv[k].y + pv[k].y;
        x[k].z = xv[k].z + pv[k].z; x[k].w = xv[k].w + pv[k].w;
    }
    if (has13) {
        x[12].x = xv[12].x + pv[12].x; x[12].y = xv[12].y + pv[12].y;
        x[12].z = xv[12].z + pv[12].z; x[12].w = xv[12].w + pv[12].w;
    } else {
        x[12] = make_float4(0.f, 0.f, 0.f, 0.f);
    }
    float4 q;
    q.x = qsv.x + qpv.x; q.y = qsv.y + qpv.y;
    q.z = qsv.z + qpv.z; q.w = qsv.w + qpv.w;

    // ---- entity partial sum ----
    float4 es = make_float4(0.f, 0.f, 0.f, 0.f);
    #pragma unroll
    for (int n = 0; n < 5; ++n) {
        es.x += ev[n].x; es.y += ev[n].y; es.z += ev[n].z; es.w += ev[n].w;
    }

    // ---- logits: per wave, shfl-reduce dot(x[s], q) over 64 lanes ----
    #pragma unroll
    for (int k = 0; k < 13; ++k) {
        if (k < 12 || has13) {
            float4 v = x[k];
            float p = v.x * q.x + v.y * q.y + v.z * q.z + v.w * q.w;
            p += __shfl_down(p, 32);
            p += __shfl_down(p, 16);
            p += __shfl_down(p, 8);
            p += __shfl_down(p, 4);
            p += __shfl_down(p, 2);
            p += __shfl_down(p, 1);
            if (c == 0) logit_s[sr + 4 * k] = p;
        }
    }
    __syncthreads();

    // ---- softmax over 50 logits (wave 0) ----
    if (sr == 0) {
        float l = (c < SENTS) ? logit_s[c] : -INFINITY;
        float mx = l;
        for (int off = 32; off >= 1; off >>= 1) mx = fmaxf(mx, __shfl_xor(mx, off));
        float ex = (c < SENTS) ? expf(l - mx) : 0.f;
        float sm = ex;
        for (int off = 32; off >= 1; off >>= 1) sm += __shfl_xor(sm, off);
        if (c < SENTS) coef[c] = ex / sm;
    }
    __syncthreads();

    // ---- h partial over this thread's rows ----
    float4 h = make_float4(0.f, 0.f, 0.f, 0.f);
    #pragma unroll
    for (int k = 0; k < 13; ++k) {
        if (k < 12 || has13) {
            float cf = coef[sr + 4 * k];
            h.x += cf * x[k].x; h.y += cf * x[k].y;
            h.z += cf * x[k].z; h.w += cf * x[k].w;
        }
    }
    part[sr][c]  = h;
    parte[sr][c] = es;
    __syncthreads();

    // ---- 4-way residue reduce + write (waves 0 and 1) ----
    if (sr == 0) {
        float4 a0 = part[0][c], a1 = part[1][c], a2 = part[2][c], a3 = part[3][c];
        float4 r;
        r.x = a0.x + a1.x + a2.x + a3.x;
        r.y = a0.y + a1.y + a2.y + a3.y;
        r.z = a0.z + a1.z + a2.z + a3.z;
        r.w = a0.w + a1.w + a2.w + a3.w;
        ((float4*)(h_out + (size_t)b * ED))[c] = r;
    } else if (sr == 1) {
        float4 a0 = parte[0][c], a1 = parte[1][c], a2 = parte[2][c], a3 = parte[3][c];
        float4 w4 = ((const float4*)dense_w)[c];
        float4 r;
        r.x = (a0.x + a1.x + a2.x + a3.x) * w4.x;
        r.y = (a0.y + a1.y + a2.y + a3.y) * w4.y;
        r.z = (a0.z + a1.z + a2.z + a3.z) * w4.z;
        r.w = (a0.w + a1.w + a2.w + a3.w) * w4.w;
        ((float4*)(m_out + (size_t)b * ED))[c] = r;
    }
}

// ---------------------------------------------------------------------------
// Kernel 2: out[b] = sigmoid( sum_e (sum_e' h[e'] A[e',e]) * m[e] + bias )
// BB batches per block; coalesced column reads of A (L2-resident).
// ---------------------------------------------------------------------------
__global__ __launch_bounds__(256) void bilinear_kernel(
    const float* __restrict__ hws, const float* __restrict__ mws,
    const float* __restrict__ A, const float* __restrict__ dense_b,
    float* __restrict__ out)
{
    __shared__ __align__(16) float hl[BB][ED];
    __shared__ float ml[BB][ED];
    __shared__ float part[BB][ED];

    int t  = threadIdx.x;
    int b0 = blockIdx.x * BB;

    for (int i = 0; i < BB; ++i) {
        hl[i][t] = hws[(size_t)(b0 + i) * ED + t];
        ml[i][t] = mws[(size_t)(b0 + i) * ED + t];
    }
    __syncthreads();

    float acc[BB];
    #pragma unroll
    for (int i = 0; i < BB; ++i) acc[i] = 0.f;

    for (int ep = 0; ep < ED; ep += 4) {
        float a0 = A[(ep + 0) * ED + t];
        float a1 = A[(ep + 1) * ED + t];
        float a2 = A[(ep + 2) * ED + t];
        float a3 = A[(ep + 3) * ED + t];
        #pragma unroll
        for (int i = 0; i < BB; ++i) {
            float4 hv = *(const float4*)&hl[i][ep];
            acc[i] += hv.x * a0 + hv.y * a1 + hv.z * a2 + hv.w * a3;
        }
    }

    #pragma unroll
    for (int i = 0; i < BB; ++i) part[i][t] = acc[i] * ml[i][t];
    __syncthreads();

    int lane = t & 63, w = t >> 6;
    float bias = dense_b[0];
    for (int i = w; i < BB; i += 4) {
        float v = part[i][lane] + part[i][lane + 64] + part[i][lane + 128] + part[i][lane + 192];
        for (int off = 32; off >= 1; off >>= 1) v += __shfl_xor(v, off);
        if (lane == 0) out[b0 + i] = 1.f / (1.f + expf(-(v + bias)));
    }
}

// ---------------------------------------------------------------------------
// Fallback: fully fused, no workspace (in case ws_size is tiny)
// ---------------------------------------------------------------------------
__global__ __launch_bounds__(256) void fused_kernel(
    const float* __restrict__ sents, const float* __restrict__ entities,
    const float* __restrict__ A, const float* __restrict__ dense_w,
    const float* __restrict__ dense_b, float* __restrict__ out)
{
    __shared__ __align__(16) float xs[SENTS][ED + 4];
    __shared__ float logit_s[64];
    __shared__ float coef[64];
    __shared__ __align__(16) float harr[ED];
    __shared__ float marr[ED];
    __shared__ float red[4];

    int t    = threadIdx.x;
    int b    = blockIdx.x;
    int lane = t & 63;
    int w    = t >> 6;

    float rate = exp2f(-(float)t * RATE_K);
    const float* sp = sents + (size_t)b * SENTS * ED;
    for (int s = 0; s < SENTS; ++s)
        xs[s][t] = sp[s * ED + t] + sinf((float)s * rate);
    __syncthreads();

    float4 q = *(const float4*)&xs[SENTS - 1][lane * 4];
    for (int s = w; s < SENTS; s += 4) {
        float4 v = *(const float4*)&xs[s][lane * 4];
        float p = v.x * q.x + v.y * q.y + v.z * q.z + v.w * q.w;
        p += __shfl_down(p, 32);
        p += __shfl_down(p, 16);
        p += __shfl_down(p, 8);
        p += __shfl_down(p, 4);
        p += __shfl_down(p, 2);
        p += __shfl_down(p, 1);
        if (lane == 0) logit_s[s] = p;
    }
    __syncthreads();

    if (w == 0) {
        float l = (lane < SENTS) ? logit_s[lane] : -INFINITY;
        float mx = l;
        for (int off = 32; off >= 1; off >>= 1) mx = fmaxf(mx, __shfl_xor(mx, off));
        float ex = (lane < SENTS) ? expf(l - mx) : 0.f;
        float sm = ex;
        for (int off = 32; off >= 1; off >>= 1) sm += __shfl_xor(sm, off);
        if (lane < SENTS) coef[lane] = ex / sm;
    }
    __syncthreads();

    float h = 0.f;
    #pragma unroll
    for (int s = 0; s < SENTS; ++s) h += coef[s] * xs[s][t];

    const float* ent = entities + (size_t)b * NENT * ED;
    float es = 0.f;
    #pragma unroll
    for (int n = 0; n < NENT; ++n) es += ent[n * ED + t];
    float m = es * dense_w[t];

    harr[t] = h;
    marr[t] = m;
    __syncthreads();

    float acc = 0.f;
    for (int ep = 0; ep < ED; ep += 4) {
        float4 hv = *(const float4*)&harr[ep];
        acc += hv.x * A[(ep + 0) * ED + t];
        acc += hv.y * A[(ep + 1) * ED + t];
        acc += hv.z * A[(ep + 2) * ED + t];
        acc += hv.w * A[(ep + 3) * ED + t];
    }
    float val = acc * marr[t];
    val += __shfl_down(val, 32);
    val += __shfl_down(val, 16);
    val += __shfl_down(val, 8);
    val += __shfl_down(val, 4);
    val += __shfl_down(val, 2);
    val += __shfl_down(val, 1);
    if (lane == 0) red[w] = val;
    __syncthreads();
    if (t == 0) {
        float tot = red[0] + red[1] + red[2] + red[3];
        out[b] = 1.f / (1.f + expf(-(tot + dense_b[0])));
    }
}

extern "C" void kernel_launch(void* const* d_in, const int* in_sizes, int n_in,
                              void* d_out, int out_size, void* d_ws, size_t ws_size,
                              hipStream_t stream) {
    const float* sents    = (const float*)d_in[0];
    const float* entities = (const float*)d_in[1];
    const float* A        = (const float*)d_in[2];
    const float* dense_w  = (const float*)d_in[3];
    const float* dense_b  = (const float*)d_in[4];
    float* out = (float*)d_out;

    size_t pos_bytes = (size_t)SENTS * ED * sizeof(float);          // 51200
    size_t hm_bytes  = (size_t)BATCH * ED * sizeof(float);          // 8 MB each
    size_t need = pos_bytes + 2 * hm_bytes;

    if (ws_size >= need) {
        float* pos_tab = (float*)d_ws;
        float* hws = (float*)((char*)d_ws + pos_bytes);
        float* mws = (float*)((char*)d_ws + pos_bytes + hm_bytes);
        pos_kernel<<<SENTS, ED, 0, stream>>>(pos_tab);
        main_kernel<<<BATCH, 256, 0, stream>>>(sents, entities, dense_w, pos_tab, hws, mws);
        bilinear_kernel<<<BATCH / BB, 256, 0, stream>>>(hws, mws, A, dense_b, out);
    } else {
        fused_kernel<<<BATCH, 256, 0, stream>>>(sents, entities, A, dense_w, dense_b, out);
    }
}

// Round 4
// 161.121 us; speedup vs baseline: 1.5316x; 1.0059x over previous
//
#include <hip/hip_runtime.h>
#include <math.h>

#define BATCH 8192
#define SENTS 50
#define ED    256
#define NENT  20
#define BB    16

// log2(200)/256
#define RATE_K 0.0298588132413075f

// ---------------------------------------------------------------------------
// Kernel 0: precompute pos[s][e] = sin(s * 200^(-e/256)) into ws table
// ---------------------------------------------------------------------------
__global__ __launch_bounds__(256) void pos_kernel(float* __restrict__ pos_tab) {
    int s = blockIdx.x;
    int e = threadIdx.x;
    float rate = exp2f(-(float)e * RATE_K);
    pos_tab[s * ED + e] = sinf((float)s * rate);
}

// ---------------------------------------------------------------------------
// Kernel E: m[b,e] = (sum_n entities[b,n,e]) * w[e].  Pure streaming reduce,
// no LDS, no barriers. Thread (b = blk*4 + t>>6, c = t&63) owns colgroup c.
// ---------------------------------------------------------------------------
__global__ __launch_bounds__(256) void ent_kernel(
    const float* __restrict__ entities, const float* __restrict__ dense_w,
    float* __restrict__ m_out)
{
    int t = threadIdx.x;
    int b = blockIdx.x * 4 + (t >> 6);
    int c = t & 63;

    const float4* e4 = (const float4*)(entities + (size_t)b * NENT * ED);

    float4 a[NENT];
    #pragma unroll
    for (int n = 0; n < NENT; ++n) a[n] = e4[n * 64 + c];

    float4 s = make_float4(0.f, 0.f, 0.f, 0.f);
    #pragma unroll
    for (int n = 0; n < NENT; ++n) {
        s.x += a[n].x; s.y += a[n].y; s.z += a[n].z; s.w += a[n].w;
    }

    float4 w4 = ((const float4*)dense_w)[c];
    s.x *= w4.x; s.y *= w4.y; s.z *= w4.z; s.w *= w4.w;
    ((float4*)(m_out + (size_t)b * ED))[c] = s;
}

// ---------------------------------------------------------------------------
// Kernel A: attention part. 512 threads = 8 waves; thread (sr=t>>6, c=t&63)
// owns float4 colgroup c of rows s = sr + 8k (6-7 rows). x in registers,
// all loads issued up front. Writes h to workspace.
// ---------------------------------------------------------------------------
__global__ __launch_bounds__(512) void attn_kernel(
    const float* __restrict__ sents, const float* __restrict__ pos_tab,
    float* __restrict__ h_out)
{
    __shared__ float logit_s[64];
    __shared__ float coef[64];
    __shared__ __align__(16) float4 part[8][64];

    int t  = threadIdx.x;
    int b  = blockIdx.x;
    int c  = t & 63;
    int sr = t >> 6;      // 0..7

    const float4* s4 = (const float4*)(sents + (size_t)b * SENTS * ED);
    const float4* p4 = (const float4*)pos_tab;

    bool has7 = (sr < 2);   // rows 48 (sr=0), 49 (sr=1)

    // ---- issue all loads up front ----
    float4 xv[7], pv[7];
    #pragma unroll
    for (int k = 0; k < 6; ++k) xv[k] = s4[(sr + 8 * k) * 64 + c];
    float4 qsv = s4[49 * 64 + c];          // redundant per wave, L1/L2 hit
    #pragma unroll
    for (int k = 0; k < 6; ++k) pv[k] = p4[(sr + 8 * k) * 64 + c];
    float4 qpv = p4[49 * 64 + c];
    if (has7) {
        xv[6] = s4[(sr + 48) * 64 + c];
        pv[6] = p4[(sr + 48) * 64 + c];
    }

    // ---- x = sents + pos ----
    float4 x[7];
    #pragma unroll
    for (int k = 0; k < 6; ++k) {
        x[k].x = xv[k].x + pv[k].x; x[k].y = xv[k].y + pv[k].y;
        x[k].z = xv[k].z + pv[k].z; x[k].w = xv[k].w + pv[k].w;
    }
    if (has7) {
        x[6].x = xv[6].x + pv[6].x; x[6].y = xv[6].y + pv[6].y;
        x[6].z = xv[6].z + pv[6].z; x[6].w = xv[6].w + pv[6].w;
    } else {
        x[6] = make_float4(0.f, 0.f, 0.f, 0.f);
    }
    float4 q;
    q.x = qsv.x + qpv.x; q.y = qsv.y + qpv.y;
    q.z = qsv.z + qpv.z; q.w = qsv.w + qpv.w;

    // ---- logits: shfl-reduce dot(x[s], q) per wave ----
    #pragma unroll
    for (int k = 0; k < 7; ++k) {
        if (k < 6 || has7) {
            float4 v = x[k];
            float p = v.x * q.x + v.y * q.y + v.z * q.z + v.w * q.w;
            p += __shfl_down(p, 32);
            p += __shfl_down(p, 16);
            p += __shfl_down(p, 8);
            p += __shfl_down(p, 4);
            p += __shfl_down(p, 2);
            p += __shfl_down(p, 1);
            if (c == 0) logit_s[sr + 8 * k] = p;
        }
    }
    __syncthreads();

    // ---- softmax over 50 logits (wave 0) ----
    if (sr == 0) {
        float l = (c < SENTS) ? logit_s[c] : -INFINITY;
        float mx = l;
        for (int off = 32; off >= 1; off >>= 1) mx = fmaxf(mx, __shfl_xor(mx, off));
        float ex = (c < SENTS) ? expf(l - mx) : 0.f;
        float sm = ex;
        for (int off = 32; off >= 1; off >>= 1) sm += __shfl_xor(sm, off);
        if (c < SENTS) coef[c] = ex / sm;
    }
    __syncthreads();

    // ---- h partial over this thread's rows ----
    float4 h = make_float4(0.f, 0.f, 0.f, 0.f);
    #pragma unroll
    for (int k = 0; k < 7; ++k) {
        if (k < 6 || has7) {
            float cf = coef[sr + 8 * k];
            h.x += cf * x[k].x; h.y += cf * x[k].y;
            h.z += cf * x[k].z; h.w += cf * x[k].w;
        }
    }
    part[sr][c] = h;
    __syncthreads();

    // ---- 8-way residue reduce + write (wave 0) ----
    if (sr == 0) {
        float4 r = make_float4(0.f, 0.f, 0.f, 0.f);
        #pragma unroll
        for (int i = 0; i < 8; ++i) {
            float4 a = part[i][c];
            r.x += a.x; r.y += a.y; r.z += a.z; r.w += a.w;
        }
        ((float4*)(h_out + (size_t)b * ED))[c] = r;
    }
}

// ---------------------------------------------------------------------------
// Kernel 2: out[b] = sigmoid( sum_e (sum_e' h[e'] A[e',e]) * m[e] + bias )
// BB batches per block; coalesced column reads of A (L2-resident).
// ---------------------------------------------------------------------------
__global__ __launch_bounds__(256) void bilinear_kernel(
    const float* __restrict__ hws, const float* __restrict__ mws,
    const float* __restrict__ A, const float* __restrict__ dense_b,
    float* __restrict__ out)
{
    __shared__ __align__(16) float hl[BB][ED];
    __shared__ float ml[BB][ED];
    __shared__ float part[BB][ED];

    int t  = threadIdx.x;
    int b0 = blockIdx.x * BB;

    for (int i = 0; i < BB; ++i) {
        hl[i][t] = hws[(size_t)(b0 + i) * ED + t];
        ml[i][t] = mws[(size_t)(b0 + i) * ED + t];
    }
    __syncthreads();

    float acc[BB];
    #pragma unroll
    for (int i = 0; i < BB; ++i) acc[i] = 0.f;

    for (int ep = 0; ep < ED; ep += 4) {
        float a0 = A[(ep + 0) * ED + t];
        float a1 = A[(ep + 1) * ED + t];
        float a2 = A[(ep + 2) * ED + t];
        float a3 = A[(ep + 3) * ED + t];
        #pragma unroll
        for (int i = 0; i < BB; ++i) {
            float4 hv = *(const float4*)&hl[i][ep];
            acc[i] += hv.x * a0 + hv.y * a1 + hv.z * a2 + hv.w * a3;
        }
    }

    #pragma unroll
    for (int i = 0; i < BB; ++i) part[i][t] = acc[i] * ml[i][t];
    __syncthreads();

    int lane = t & 63, w = t >> 6;
    float bias = dense_b[0];
    for (int i = w; i < BB; i += 4) {
        float v = part[i][lane] + part[i][lane + 64] + part[i][lane + 128] + part[i][lane + 192];
        for (int off = 32; off >= 1; off >>= 1) v += __shfl_xor(v, off);
        if (lane == 0) out[b0 + i] = 1.f / (1.f + expf(-(v + bias)));
    }
}

// ---------------------------------------------------------------------------
// Fallback: fully fused, no workspace (in case ws_size is tiny)
// ---------------------------------------------------------------------------
__global__ __launch_bounds__(256) void fused_kernel(
    const float* __restrict__ sents, const float* __restrict__ entities,
    const float* __restrict__ A, const float* __restrict__ dense_w,
    const float* __restrict__ dense_b, float* __restrict__ out)
{
    __shared__ __align__(16) float xs[SENTS][ED + 4];
    __shared__ float logit_s[64];
    __shared__ float coef[64];
    __shared__ __align__(16) float harr[ED];
    __shared__ float marr[ED];
    __shared__ float red[4];

    int t    = threadIdx.x;
    int b    = blockIdx.x;
    int lane = t & 63;
    int w    = t >> 6;

    float rate = exp2f(-(float)t * RATE_K);
    const float* sp = sents + (size_t)b * SENTS * ED;
    for (int s = 0; s < SENTS; ++s)
        xs[s][t] = sp[s * ED + t] + sinf((float)s * rate);
    __syncthreads();

    float4 q = *(const float4*)&xs[SENTS - 1][lane * 4];
    for (int s = w; s < SENTS; s += 4) {
        float4 v = *(const float4*)&xs[s][lane * 4];
        float p = v.x * q.x + v.y * q.y + v.z * q.z + v.w * q.w;
        p += __shfl_down(p, 32);
        p += __shfl_down(p, 16);
        p += __shfl_down(p, 8);
        p += __shfl_down(p, 4);
        p += __shfl_down(p, 2);
        p += __shfl_down(p, 1);
        if (lane == 0) logit_s[s] = p;
    }
    __syncthreads();

    if (w == 0) {
        float l = (lane < SENTS) ? logit_s[lane] : -INFINITY;
        float mx = l;
        for (int off = 32; off >= 1; off >>= 1) mx = fmaxf(mx, __shfl_xor(mx, off));
        float ex = (lane < SENTS) ? expf(l - mx) : 0.f;
        float sm = ex;
        for (int off = 32; off >= 1; off >>= 1) sm += __shfl_xor(sm, off);
        if (lane < SENTS) coef[lane] = ex / sm;
    }
    __syncthreads();

    float h = 0.f;
    #pragma unroll
    for (int s = 0; s < SENTS; ++s) h += coef[s] * xs[s][t];

    const float* ent = entities + (size_t)b * NENT * ED;
    float es = 0.f;
    #pragma unroll
    for (int n = 0; n < NENT; ++n) es += ent[n * ED + t];
    float m = es * dense_w[t];

    harr[t] = h;
    marr[t] = m;
    __syncthreads();

    float acc = 0.f;
    for (int ep = 0; ep < ED; ep += 4) {
        float4 hv = *(const float4*)&harr[ep];
        acc += hv.x * A[(ep + 0) * ED + t];
        acc += hv.y * A[(ep + 1) * ED + t];
        acc += hv.z * A[(ep + 2) * ED + t];
        acc += hv.w * A[(ep + 3) * ED + t];
    }
    float val = acc * marr[t];
    val += __shfl_down(val, 32);
    val += __shfl_down(val, 16);
    val += __shfl_down(val, 8);
    val += __shfl_down(val, 4);
    val += __shfl_down(val, 2);
    val += __shfl_down(val, 1);
    if (lane == 0) red[w] = val;
    __syncthreads();
    if (t == 0) {
        float tot = red[0] + red[1] + red[2] + red[3];
        out[b] = 1.f / (1.f + expf(-(tot + dense_b[0])));
    }
}

extern "C" void kernel_launch(void* const* d_in, const int* in_sizes, int n_in,
                              void* d_out, int out_size, void* d_ws, size_t ws_size,
                              hipStream_t stream) {
    const float* sents    = (const float*)d_in[0];
    const float* entities = (const float*)d_in[1];
    const float* A        = (const float*)d_in[2];
    const float* dense_w  = (const float*)d_in[3];
    const float* dense_b  = (const float*)d_in[4];
    float* out = (float*)d_out;

    size_t pos_bytes = (size_t)SENTS * ED * sizeof(float);          // 51200
    size_t hm_bytes  = (size_t)BATCH * ED * sizeof(float);          // 8 MB each
    size_t need = pos_bytes + 2 * hm_bytes;

    if (ws_size >= need) {
        float* pos_tab = (float*)d_ws;
        float* hws = (float*)((char*)d_ws + pos_bytes);
        float* mws = (float*)((char*)d_ws + pos_bytes + hm_bytes);
        pos_kernel<<<SENTS, ED, 0, stream>>>(pos_tab);
        ent_kernel<<<BATCH / 4, 256, 0, stream>>>(entities, dense_w, mws);
        attn_kernel<<<BATCH, 512, 0, stream>>>(sents, pos_tab, hws);
        bilinear_kernel<<<BATCH / BB, 256, 0, stream>>>(hws, mws, A, dense_b, out);
    } else {
        fused_kernel<<<BATCH, 256, 0, stream>>>(sents, entities, A, dense_w, dense_b, out);
    }
}

// Round 5
// 147.561 us; speedup vs baseline: 1.6723x; 1.0919x over previous
//
#include <hip/hip_runtime.h>
#include <math.h>

#define BATCH 8192
#define SENTS 50
#define ED    256
#define NENT  20
#define BB    16

// log2(200)/256
#define RATE_K 0.0298588132413075f

// ---------------------------------------------------------------------------
// Kernel A: fused attention + entity reduce. 512 threads = 8 waves.
// Thread (sr=t>>6, c=t&63) owns float4 colgroup c of x-rows s = sr+8k
// (6-7 rows) and entity rows sr, sr+8, sr+16(<20). pos computed on the fly
// (exp2f+__sinf) — no pos table, no pos loads. All global loads up front.
// ---------------------------------------------------------------------------
__global__ __launch_bounds__(512, 6) void attn_ent_kernel(
    const float* __restrict__ sents, const float* __restrict__ entities,
    const float* __restrict__ dense_w,
    float* __restrict__ h_out, float* __restrict__ m_out)
{
    __shared__ float logit_s[64];
    __shared__ float coef[64];
    __shared__ __align__(16) float4 part[8][64];
    __shared__ __align__(16) float4 parte[8][64];

    int t  = threadIdx.x;
    int b  = blockIdx.x;
    int c  = t & 63;
    int sr = t >> 6;      // 0..7

    const float4* s4 = (const float4*)(sents + (size_t)b * SENTS * ED);
    const float4* e4 = (const float4*)(entities + (size_t)b * NENT * ED);

    bool has7 = (sr < 2);   // rows 48 (sr=0), 49 (sr=1)

    // ---- issue ALL global loads up front ----
    float4 xv[7];
    #pragma unroll
    for (int k = 0; k < 6; ++k) xv[k] = s4[(sr + 8 * k) * 64 + c];
    float4 qsv = s4[49 * 64 + c];          // redundant per wave, L1 hit
    float4 ev0 = e4[(sr     ) * 64 + c];
    float4 ev1 = e4[(sr +  8) * 64 + c];
    float4 ev2 = make_float4(0.f, 0.f, 0.f, 0.f);
    if (sr < 4) ev2 = e4[(sr + 16) * 64 + c];
    if (has7) xv[6] = s4[(sr + 48) * 64 + c];

    // ---- per-column rates (VALU overlaps load latency) ----
    float4 rate;
    rate.x = exp2f(-(float)(4 * c + 0) * RATE_K);
    rate.y = exp2f(-(float)(4 * c + 1) * RATE_K);
    rate.z = exp2f(-(float)(4 * c + 2) * RATE_K);
    rate.w = exp2f(-(float)(4 * c + 3) * RATE_K);

    // ---- q = sents[49] + pos[49] ----
    float4 q;
    q.x = qsv.x + __sinf(49.f * rate.x);
    q.y = qsv.y + __sinf(49.f * rate.y);
    q.z = qsv.z + __sinf(49.f * rate.z);
    q.w = qsv.w + __sinf(49.f * rate.w);

    // ---- x[k] = sents[sr+8k] + sin((sr+8k)*rate) ----
    float4 x[7];
    #pragma unroll
    for (int k = 0; k < 7; ++k) {
        if (k < 6 || has7) {
            float fs = (float)(sr + 8 * k);
            x[k].x = xv[k].x + __sinf(fs * rate.x);
            x[k].y = xv[k].y + __sinf(fs * rate.y);
            x[k].z = xv[k].z + __sinf(fs * rate.z);
            x[k].w = xv[k].w + __sinf(fs * rate.w);
        } else {
            x[k] = make_float4(0.f, 0.f, 0.f, 0.f);
        }
    }

    // ---- entity partial sum ----
    float4 es;
    es.x = ev0.x + ev1.x + ev2.x;
    es.y = ev0.y + ev1.y + ev2.y;
    es.z = ev0.z + ev1.z + ev2.z;
    es.w = ev0.w + ev1.w + ev2.w;

    // ---- logits: shfl-reduce dot(x[s], q) per wave ----
    #pragma unroll
    for (int k = 0; k < 7; ++k) {
        if (k < 6 || has7) {
            float4 v = x[k];
            float p = v.x * q.x + v.y * q.y + v.z * q.z + v.w * q.w;
            p += __shfl_down(p, 32);
            p += __shfl_down(p, 16);
            p += __shfl_down(p, 8);
            p += __shfl_down(p, 4);
            p += __shfl_down(p, 2);
            p += __shfl_down(p, 1);
            if (c == 0) logit_s[sr + 8 * k] = p;
        }
    }
    __syncthreads();

    // ---- softmax over 50 logits (wave 0) ----
    if (sr == 0) {
        float l = (c < SENTS) ? logit_s[c] : -INFINITY;
        float mx = l;
        for (int off = 32; off >= 1; off >>= 1) mx = fmaxf(mx, __shfl_xor(mx, off));
        float ex = (c < SENTS) ? expf(l - mx) : 0.f;
        float sm = ex;
        for (int off = 32; off >= 1; off >>= 1) sm += __shfl_xor(sm, off);
        if (c < SENTS) coef[c] = ex / sm;
    }
    __syncthreads();

    // ---- h partial over this thread's rows ----
    float4 h = make_float4(0.f, 0.f, 0.f, 0.f);
    #pragma unroll
    for (int k = 0; k < 7; ++k) {
        if (k < 6 || has7) {
            float cf = coef[sr + 8 * k];
            h.x += cf * x[k].x; h.y += cf * x[k].y;
            h.z += cf * x[k].z; h.w += cf * x[k].w;
        }
    }
    part[sr][c]  = h;
    parte[sr][c] = es;
    __syncthreads();

    // ---- 8-way residue reduce + write (waves 0 and 1) ----
    if (sr == 0) {
        float4 r = make_float4(0.f, 0.f, 0.f, 0.f);
        #pragma unroll
        for (int i = 0; i < 8; ++i) {
            float4 a = part[i][c];
            r.x += a.x; r.y += a.y; r.z += a.z; r.w += a.w;
        }
        ((float4*)(h_out + (size_t)b * ED))[c] = r;
    } else if (sr == 1) {
        float4 r = make_float4(0.f, 0.f, 0.f, 0.f);
        #pragma unroll
        for (int i = 0; i < 8; ++i) {
            float4 a = parte[i][c];
            r.x += a.x; r.y += a.y; r.z += a.z; r.w += a.w;
        }
        float4 w4 = ((const float4*)dense_w)[c];
        r.x *= w4.x; r.y *= w4.y; r.z *= w4.z; r.w *= w4.w;
        ((float4*)(m_out + (size_t)b * ED))[c] = r;
    }
}

// ---------------------------------------------------------------------------
// Kernel 2: out[b] = sigmoid( sum_e (sum_e' h[e'] A[e',e]) * m[e] + bias )
// BB batches per block; coalesced column reads of A (L2-resident).
// ---------------------------------------------------------------------------
__global__ __launch_bounds__(256) void bilinear_kernel(
    const float* __restrict__ hws, const float* __restrict__ mws,
    const float* __restrict__ A, const float* __restrict__ dense_b,
    float* __restrict__ out)
{
    __shared__ __align__(16) float hl[BB][ED];
    __shared__ float ml[BB][ED];
    __shared__ float part[BB][ED];

    int t  = threadIdx.x;
    int b0 = blockIdx.x * BB;

    for (int i = 0; i < BB; ++i) {
        hl[i][t] = hws[(size_t)(b0 + i) * ED + t];
        ml[i][t] = mws[(size_t)(b0 + i) * ED + t];
    }
    __syncthreads();

    float acc[BB];
    #pragma unroll
    for (int i = 0; i < BB; ++i) acc[i] = 0.f;

    for (int ep = 0; ep < ED; ep += 4) {
        float a0 = A[(ep + 0) * ED + t];
        float a1 = A[(ep + 1) * ED + t];
        float a2 = A[(ep + 2) * ED + t];
        float a3 = A[(ep + 3) * ED + t];
        #pragma unroll
        for (int i = 0; i < BB; ++i) {
            float4 hv = *(const float4*)&hl[i][ep];
            acc[i] += hv.x * a0 + hv.y * a1 + hv.z * a2 + hv.w * a3;
        }
    }

    #pragma unroll
    for (int i = 0; i < BB; ++i) part[i][t] = acc[i] * ml[i][t];
    __syncthreads();

    int lane = t & 63, w = t >> 6;
    float bias = dense_b[0];
    for (int i = w; i < BB; i += 4) {
        float v = part[i][lane] + part[i][lane + 64] + part[i][lane + 128] + part[i][lane + 192];
        for (int off = 32; off >= 1; off >>= 1) v += __shfl_xor(v, off);
        if (lane == 0) out[b0 + i] = 1.f / (1.f + expf(-(v + bias)));
    }
}

// ---------------------------------------------------------------------------
// Fallback: fully fused, no workspace (in case ws_size is tiny)
// ---------------------------------------------------------------------------
__global__ __launch_bounds__(256) void fused_kernel(
    const float* __restrict__ sents, const float* __restrict__ entities,
    const float* __restrict__ A, const float* __restrict__ dense_w,
    const float* __restrict__ dense_b, float* __restrict__ out)
{
    __shared__ __align__(16) float xs[SENTS][ED + 4];
    __shared__ float logit_s[64];
    __shared__ float coef[64];
    __shared__ __align__(16) float harr[ED];
    __shared__ float marr[ED];
    __shared__ float red[4];

    int t    = threadIdx.x;
    int b    = blockIdx.x;
    int lane = t & 63;
    int w    = t >> 6;

    float rate = exp2f(-(float)t * RATE_K);
    const float* sp = sents + (size_t)b * SENTS * ED;
    for (int s = 0; s < SENTS; ++s)
        xs[s][t] = sp[s * ED + t] + sinf((float)s * rate);
    __syncthreads();

    float4 q = *(const float4*)&xs[SENTS - 1][lane * 4];
    for (int s = w; s < SENTS; s += 4) {
        float4 v = *(const float4*)&xs[s][lane * 4];
        float p = v.x * q.x + v.y * q.y + v.z * q.z + v.w * q.w;
        p += __shfl_down(p, 32);
        p += __shfl_down(p, 16);
        p += __shfl_down(p, 8);
        p += __shfl_down(p, 4);
        p += __shfl_down(p, 2);
        p += __shfl_down(p, 1);
        if (lane == 0) logit_s[s] = p;
    }
    __syncthreads();

    if (w == 0) {
        float l = (lane < SENTS) ? logit_s[lane] : -INFINITY;
        float mx = l;
        for (int off = 32; off >= 1; off >>= 1) mx = fmaxf(mx, __shfl_xor(mx, off));
        float ex = (lane < SENTS) ? expf(l - mx) : 0.f;
        float sm = ex;
        for (int off = 32; off >= 1; off >>= 1) sm += __shfl_xor(sm, off);
        if (lane < SENTS) coef[lane] = ex / sm;
    }
    __syncthreads();

    float h = 0.f;
    #pragma unroll
    for (int s = 0; s < SENTS; ++s) h += coef[s] * xs[s][t];

    const float* ent = entities + (size_t)b * NENT * ED;
    float es = 0.f;
    #pragma unroll
    for (int n = 0; n < NENT; ++n) es += ent[n * ED + t];
    float m = es * dense_w[t];

    harr[t] = h;
    marr[t] = m;
    __syncthreads();

    float acc = 0.f;
    for (int ep = 0; ep < ED; ep += 4) {
        float4 hv = *(const float4*)&harr[ep];
        acc += hv.x * A[(ep + 0) * ED + t];
        acc += hv.y * A[(ep + 1) * ED + t];
        acc += hv.z * A[(ep + 2) * ED + t];
        acc += hv.w * A[(ep + 3) * ED + t];
    }
    float val = acc * marr[t];
    val += __shfl_down(val, 32);
    val += __shfl_down(val, 16);
    val += __shfl_down(val, 8);
    val += __shfl_down(val, 4);
    val += __shfl_down(val, 2);
    val += __shfl_down(val, 1);
    if (lane == 0) red[w] = val;
    __syncthreads();
    if (t == 0) {
        float tot = red[0] + red[1] + red[2] + red[3];
        out[b] = 1.f / (1.f + expf(-(tot + dense_b[0])));
    }
}

extern "C" void kernel_launch(void* const* d_in, const int* in_sizes, int n_in,
                              void* d_out, int out_size, void* d_ws, size_t ws_size,
                              hipStream_t stream) {
    const float* sents    = (const float*)d_in[0];
    const float* entities = (const float*)d_in[1];
    const float* A        = (const float*)d_in[2];
    const float* dense_w  = (const float*)d_in[3];
    const float* dense_b  = (const float*)d_in[4];
    float* out = (float*)d_out;

    size_t hm_bytes = (size_t)BATCH * ED * sizeof(float);           // 8 MB each
    size_t need = 2 * hm_bytes;

    if (ws_size >= need) {
        float* hws = (float*)d_ws;
        float* mws = (float*)((char*)d_ws + hm_bytes);
        attn_ent_kernel<<<BATCH, 512, 0, stream>>>(sents, entities, dense_w, hws, mws);
        bilinear_kernel<<<BATCH / BB, 256, 0, stream>>>(hws, mws, A, dense_b, out);
    } else {
        fused_kernel<<<BATCH, 256, 0, stream>>>(sents, entities, A, dense_w, dense_b, out);
    }
}